// Round 1
// baseline (574.470 us; speedup 1.0000x reference)
//
#include <hip/hip_runtime.h>

#define N_  16
#define T_  1024
#define D_  2000
#define K_  21
#define P_  10
#define NT_ (N_*T_)   // 16384

// ---------------- K0: pad W rows [D][21] -> [D][24] (16B-aligned rows) ----
__global__ void k_padW(const float* __restrict__ W0, const float* __restrict__ W1,
                       float* __restrict__ W0p, float* __restrict__ W1p) {
    int gid = blockIdx.x * blockDim.x + threadIdx.x;
    if (gid >= D_ * 24) return;
    int d = gid / 24, kk = gid - d * 24;
    float v0 = (kk < K_) ? W0[d * K_ + kk] : 0.f;
    float v1 = (kk < K_) ? W1[d * K_ + kk] : 0.f;
    W0p[gid] = v0;
    W1p[gid] = v1;
}

// ---------------- K1: one pass over x -> w0, M, w1p -----------------------
// w0[r,k]  = sum_{d<2000} x[r,d]*W0[d,k]
// M[r,k]   = sum_{d<1000} x[r,d]*W1[d,k]
// w1p[r,k] = sum_{d>=1000} x[r,d]*W1[d,k]
// block: 64 rows, 256 threads. lane_t = tid&63 owns row t; q = tid>>6 owns a
// 64-wide d-quarter of each 256-wide tile. x staged transposed via LDS so the
// d-loop is wave-uniform (uniform W row loads) and no cross-lane reduction.
__global__ __launch_bounds__(256)
void k_gemm_small(const float* __restrict__ x,
                  const float* __restrict__ W0p, const float* __restrict__ W1p,
                  float* __restrict__ w0o, float* __restrict__ Mo,
                  float* __restrict__ w1po) {
    __shared__ float xs[2][64][257];   // +1 pad: conflict-free b32 access, 131.6 KB
    const int tid = threadIdx.x;
    const int r0 = blockIdx.x * 64;
    const int lane_t = tid & 63;
    const int q = __builtin_amdgcn_readfirstlane(tid >> 6);   // wave id, uniform

    float acc0[K_], accM[K_], accP[K_];
#pragma unroll
    for (int k = 0; k < K_; ++k) { acc0[k] = 0.f; accM[k] = 0.f; accP[k] = 0.f; }

    const int s_col = tid & 15;    // f4-col group base
    const int s_row = tid >> 4;    // 0..15
    float4 regs[4][4];

    auto load_tile = [&](int dt) {
#pragma unroll
        for (int p = 0; p < 4; ++p) {
            int row = s_row + 16 * p;           // 0..63
#pragma unroll
            for (int c4 = 0; c4 < 4; ++c4) {
                int dof = (s_col + 16 * c4) * 4;  // 0..252
                float4 v = make_float4(0.f, 0.f, 0.f, 0.f);
                if (dt + dof < D_)
                    v = *reinterpret_cast<const float4*>(
                        x + (size_t)(r0 + row) * D_ + dt + dof);
                regs[p][c4] = v;
            }
        }
    };
    auto write_tile = [&](int buf) {
#pragma unroll
        for (int p = 0; p < 4; ++p) {
            int row = s_row + 16 * p;
#pragma unroll
            for (int c4 = 0; c4 < 4; ++c4) {
                int c = (s_col + 16 * c4) * 4;
                xs[buf][row][c + 0] = regs[p][c4].x;
                xs[buf][row][c + 1] = regs[p][c4].y;
                xs[buf][row][c + 2] = regs[p][c4].z;
                xs[buf][row][c + 3] = regs[p][c4].w;
            }
        }
    };

    load_tile(0);
    write_tile(0);
    __syncthreads();

    for (int ti = 0; ti < 8; ++ti) {
        const int dt = ti * 256;
        if (ti < 7) load_tile(dt + 256);          // prefetch next tile -> regs
        const int tw = min(256, D_ - dt);
        const int lo = q * 64;
        const int hi = min(lo + 64, tw);
        const int buf = ti & 1;
        for (int c = lo; c < hi; ++c) {
            const int d = dt + c;                 // wave-uniform
            const float xv = xs[buf][lane_t][c];
            const float4* w0r = reinterpret_cast<const float4*>(W0p + d * 24);
            const float4* w1r = reinterpret_cast<const float4*>(W1p + d * 24);
            float wa[24], wb[24];
#pragma unroll
            for (int j = 0; j < 5; ++j) {
                *reinterpret_cast<float4*>(&wa[4 * j]) = w0r[j];
                *reinterpret_cast<float4*>(&wb[4 * j]) = w1r[j];
            }
            wa[20] = W0p[d * 24 + 20];
            wb[20] = W1p[d * 24 + 20];
#pragma unroll
            for (int k = 0; k < K_; ++k) acc0[k] = fmaf(xv, wa[k], acc0[k]);
            if (d < 1000) {
#pragma unroll
                for (int k = 0; k < K_; ++k) accM[k] = fmaf(xv, wb[k], accM[k]);
            } else {
#pragma unroll
                for (int k = 0; k < K_; ++k) accP[k] = fmaf(xv, wb[k], accP[k]);
            }
        }
        if (ti < 7) write_tile((ti + 1) & 1);     // other buffer: safe pre-barrier
        __syncthreads();
    }

    // 4-way cross-wave reduction via LDS (overlay on xs), then store.
    float* red = &xs[0][0][0];                    // needs 256*21 floats
#define REDUCE_STORE(ACC, DST)                                                  \
    __syncthreads();                                                            \
    _Pragma("unroll")                                                           \
    for (int k = 0; k < K_; ++k) red[tid * K_ + k] = ACC[k];                    \
    __syncthreads();                                                            \
    for (int o = tid; o < 64 * K_; o += 256) {                                  \
        int t = o / K_, k = o - t * K_;                                         \
        float s = red[t * K_ + k] + red[(64 + t) * K_ + k] +                    \
                  red[(128 + t) * K_ + k] + red[(192 + t) * K_ + k];            \
        DST[(size_t)(r0 + t) * K_ + k] = s;                                     \
    }
    REDUCE_STORE(acc0, w0o)
    REDUCE_STORE(accM, Mo)
    REDUCE_STORE(accP, w1po)
#undef REDUCE_STORE
}

// ---------------- K1.5: w1 = w1p + conv21(w0, M) ---------------------------
__global__ void k_w1(const float* __restrict__ w0, const float* __restrict__ Mv,
                     const float* __restrict__ w1p, float* __restrict__ w1) {
    int o = blockIdx.x * blockDim.x + threadIdx.x;
    if (o >= NT_ * K_) return;
    int row = o / K_, k = o - row * K_;
    int t = row & (T_ - 1);
    float acc = w1p[o];
#pragma unroll
    for (int j = 0; j < K_; ++j) {
        int tt = t + j - P_;
        if (tt >= 0 && tt < T_)
            acc = fmaf(w0[row * K_ + j], Mv[(size_t)(row + j - P_) * K_ + k], acc);
    }
    w1[o] = acc;
}

// ---------------- K2/K3 fused: shift-conv over one channel group -----------
// grid 4096: bit11 selects group (coef/dbase); per block: (n, 64-t-chunk,
// 128-wide d-segment). x halo tile (84 rows) staged in LDS; each thread
// register-blocks G=8 consecutive t outputs for one f4 column.
__global__ __launch_bounds__(256)
void k_conv(const float* __restrict__ x, const float* __restrict__ w0,
            const float* __restrict__ w1, float* __restrict__ out) {
    __shared__ float xsl[84][128];     // 43 KB
    __shared__ float wc[64 * K_];      // 5.4 KB
    const int b = blockIdx.x;
    const int grp = b >> 11;
    const float* __restrict__ coef = grp ? w1 : w0;
    const int dbase = grp * 1000;
    const int bb = b & 2047;
    const int dseg = bb & 7;
    const int tch = (bb >> 3) & 15;
    const int nn = bb >> 7;
    const int t0 = tch * 64;
    const int tid = threadIdx.x;
    const float* xb = x + (size_t)nn * T_ * D_;

    // stage x rows [t0-10, t0+74) of group cols [dseg*128, +128)
    {
        const int scol = tid & 31, srow0 = tid >> 5;
        for (int pass = 0; pass < 11; ++pass) {
            int r = srow0 + pass * 8;
            if (r < 84) {
                int u = t0 - P_ + r;
                int dl = dseg * 128 + scol * 4;   // local d within group
                float4 v = make_float4(0.f, 0.f, 0.f, 0.f);
                if (u >= 0 && u < T_ && dl < 1000)
                    v = *reinterpret_cast<const float4*>(xb + (size_t)u * D_ + dbase + dl);
                *reinterpret_cast<float4*>(&xsl[r][scol * 4]) = v;
            }
        }
    }
    // stage coefficients for this t-chunk
    for (int o = tid; o < 64 * K_; o += 256) {
        int tl = o / K_, k = o - tl * K_;
        wc[o] = coef[((size_t)nn * T_ + t0 + tl) * K_ + k];
    }
    __syncthreads();

    const int col = tid & 31;        // f4 column
    const int tsub = tid >> 5;       // 0..7
    const int tl0 = tsub * 8;
    float4 acc[8];
#pragma unroll
    for (int g = 0; g < 8; ++g) acc[g] = make_float4(0.f, 0.f, 0.f, 0.f);

    for (int ul = 0; ul < 28; ++ul) {
        const int r = tl0 + ul;                    // xsl row (= x row t0-10+r)
        const float4 xf = *reinterpret_cast<const float4*>(&xsl[r][col * 4]);
#pragma unroll
        for (int g = 0; g < 8; ++g) {
            const int k = ul - g;
            float c = (k >= 0 && k < K_) ? wc[(tl0 + g) * K_ + k] : 0.f;
            acc[g].x = fmaf(c, xf.x, acc[g].x);
            acc[g].y = fmaf(c, xf.y, acc[g].y);
            acc[g].z = fmaf(c, xf.z, acc[g].z);
            acc[g].w = fmaf(c, xf.w, acc[g].w);
        }
    }

    const int dl = dseg * 128 + col * 4;
    if (dl < 1000) {
#pragma unroll
        for (int g = 0; g < 8; ++g) {
            float* dst = out + ((size_t)nn * T_ + t0 + tl0 + g) * D_ + dbase + dl;
            *reinterpret_cast<float4*>(dst) = acc[g];
        }
    }
}

extern "C" void kernel_launch(void* const* d_in, const int* in_sizes, int n_in,
                              void* d_out, int out_size, void* d_ws, size_t ws_size,
                              hipStream_t stream) {
    const float* x  = (const float*)d_in[0];
    const float* W0 = (const float*)d_in[1];
    const float* W1 = (const float*)d_in[2];
    float* out = (float*)d_out;
    float* ws  = (float*)d_ws;

    float* W0p = ws;                        // 2000*24 = 48000
    float* W1p = ws + 48000;                // 48000
    float* w0  = ws + 96000;                // 16384*21 = 344064
    float* Mv  = ws + 96000 + 344064;       // 344064
    float* w1p = ws + 96000 + 2 * 344064;   // 344064
    float* w1  = ws + 96000 + 3 * 344064;   // 344064  (total ~5.9 MB)

    hipLaunchKernelGGL(k_padW, dim3(188), dim3(256), 0, stream, W0, W1, W0p, W1p);
    hipLaunchKernelGGL(k_gemm_small, dim3(256), dim3(256), 0, stream,
                       x, W0p, W1p, w0, Mv, w1p);
    hipLaunchKernelGGL(k_w1, dim3(1344), dim3(256), 0, stream, w0, Mv, w1p, w1);
    hipLaunchKernelGGL(k_conv, dim3(4096), dim3(256), 0, stream, x, w0, w1, out);
}

// Round 2
// 388.407 us; speedup vs baseline: 1.4790x; 1.4790x over previous
//
#include <hip/hip_runtime.h>

#define N_  16
#define T_  1024
#define D_  2000
#define K_  21
#define P_  10
#define NT_ (N_*T_)   // 16384

// ---------------- K0: pad W rows [D][21] -> [D][24] (aligned rows) --------
__global__ void k_padW(const float* __restrict__ W0, const float* __restrict__ W1,
                       float* __restrict__ W0p, float* __restrict__ W1p) {
    int gid = blockIdx.x * blockDim.x + threadIdx.x;
    if (gid >= D_ * 24) return;
    int d = gid / 24, kk = gid - d * 24;
    float v0 = (kk < K_) ? W0[d * K_ + kk] : 0.f;
    float v1 = (kk < K_) ? W1[d * K_ + kk] : 0.f;
    W0p[gid] = v0;
    W1p[gid] = v1;
}

// ---------------- K1: coefficient GEMM, lane-owns-row, scalar W -----------
// Each block: 64 rows (lane = row), h = quarter of d-range; wave w handles a
// 128/116-wide d-strip. x read direct per-lane float4 (line consumed over 8
// iters -> full HBM efficiency). W rows are wave-uniform -> scalar loads.
// Outputs: per-(h) partial buffers; w0 gets 4 partials, M gets 2, P gets 2.
__global__ __launch_bounds__(256)
void k_coef(const float* __restrict__ x,
            const float* __restrict__ W0p, const float* __restrict__ W1p,
            float* __restrict__ q0, float* __restrict__ q1,
            float* __restrict__ q2, float* __restrict__ q3,
            float* __restrict__ Ma, float* __restrict__ Mb,
            float* __restrict__ Pa, float* __restrict__ Pb) {
    __shared__ float red[256 * 22];        // 22.5 KB -> 4+ blocks/CU
    const int tid  = threadIdx.x;
    const int lane = tid & 63;
    const int w    = tid >> 6;             // wave id 0..3
    const int rg   = blockIdx.x >> 2;      // 0..255  (64-row group)
    const int h    = blockIdx.x & 3;       // quarter 0..3
    const int r    = rg * 64 + lane;

    const int starts[4] = {0, 128, 256, 384};
    const int widths[4] = {128, 128, 128, 116};
    const int ds = h * 500 + starts[w];
    const int n4 = widths[w] >> 2;

    float a0[K_], ab[K_];
#pragma unroll
    for (int k = 0; k < K_; ++k) { a0[k] = 0.f; ab[k] = 0.f; }

    const float* __restrict__ xr = x + (size_t)r * D_ + ds;

#pragma unroll 2
    for (int i = 0; i < n4; ++i) {
        const float4 xv = *reinterpret_cast<const float4*>(xr + i * 4);
        const int dbase = ds + i * 4;
#pragma unroll
        for (int j = 0; j < 4; ++j) {
            const int du = __builtin_amdgcn_readfirstlane(dbase + j);
            const float* __restrict__ wr0 = W0p + du * 24;
            const float* __restrict__ wr1 = W1p + du * 24;
            const float xs = (j == 0) ? xv.x : (j == 1) ? xv.y : (j == 2) ? xv.z : xv.w;
#pragma unroll
            for (int k = 0; k < K_; ++k) a0[k] = fmaf(xs, wr0[k], a0[k]);
#pragma unroll
            for (int k = 0; k < K_; ++k) ab[k] = fmaf(xs, wr1[k], ab[k]);
        }
    }

    float* const w0dst[4] = {q0, q1, q2, q3};
    float* const mpdst[4] = {Ma, Mb, Pa, Pb};

    // pass A: w0 partial
#pragma unroll
    for (int k = 0; k < K_; ++k) red[tid * 22 + k] = a0[k];
    __syncthreads();
    for (int o = tid; o < 64 * K_; o += 256) {
        int t = o / K_, j = o - t * K_;
        float s = red[t * 22 + j] + red[(64 + t) * 22 + j] +
                  red[(128 + t) * 22 + j] + red[(192 + t) * 22 + j];
        w0dst[h][(size_t)(rg * 64 + t) * K_ + j] = s;
    }
    __syncthreads();
    // pass B: M/P partial
#pragma unroll
    for (int k = 0; k < K_; ++k) red[tid * 22 + k] = ab[k];
    __syncthreads();
    for (int o = tid; o < 64 * K_; o += 256) {
        int t = o / K_, j = o - t * K_;
        float s = red[t * 22 + j] + red[(64 + t) * 22 + j] +
                  red[(128 + t) * 22 + j] + red[(192 + t) * 22 + j];
        mpdst[h][(size_t)(rg * 64 + t) * K_ + j] = s;
    }
}

// ---------------- K1.5: finalize w0, compute w1 ---------------------------
// w0 = q0+q1+q2+q3 ; M = Ma+Mb ; P = Pa+Pb
// w1[row,k] = P[row,k] + sum_j w0[row,j] * M[row+j-10, k]
__global__ void k_finish(const float* __restrict__ q0, const float* __restrict__ q1,
                         const float* __restrict__ q2, const float* __restrict__ q3,
                         const float* __restrict__ Ma, const float* __restrict__ Mb,
                         const float* __restrict__ Pa, const float* __restrict__ Pb,
                         float* __restrict__ w0f, float* __restrict__ w1f) {
    int o = blockIdx.x * blockDim.x + threadIdx.x;
    if (o >= NT_ * K_) return;
    int row = o / K_, k = o - row * K_;
    int t = row & (T_ - 1);

    const size_t rb = (size_t)row * K_;
    float w0row[K_];
#pragma unroll
    for (int j = 0; j < K_; ++j)
        w0row[j] = q0[rb + j] + q1[rb + j] + q2[rb + j] + q3[rb + j];
    w0f[o] = w0row[k];

    float acc = Pa[o] + Pb[o];
#pragma unroll
    for (int j = 0; j < K_; ++j) {
        int tt = t + j - P_;
        if (tt >= 0 && tt < T_) {
            size_t ro = (size_t)(row + j - P_) * K_ + k;
            acc = fmaf(w0row[j], Ma[ro] + Mb[ro], acc);
        }
    }
    w1f[o] = acc;
}

// ---------------- K2/K3 fused: shift-conv over one channel group -----------
__global__ __launch_bounds__(256)
void k_conv(const float* __restrict__ x, const float* __restrict__ w0,
            const float* __restrict__ w1, float* __restrict__ out) {
    __shared__ float xsl[84][128];     // 43 KB
    __shared__ float wc[64 * K_];      // 5.4 KB
    const int b = blockIdx.x;
    const int grp = b >> 11;
    const float* __restrict__ coef = grp ? w1 : w0;
    const int dbase = grp * 1000;
    const int bb = b & 2047;
    const int dseg = bb & 7;
    const int tch = (bb >> 3) & 15;
    const int nn = bb >> 7;
    const int t0 = tch * 64;
    const int tid = threadIdx.x;
    const float* xb = x + (size_t)nn * T_ * D_;

    {
        const int scol = tid & 31, srow0 = tid >> 5;
#pragma unroll
        for (int pass = 0; pass < 11; ++pass) {
            int rr = srow0 + pass * 8;
            if (rr < 84) {
                int u = t0 - P_ + rr;
                int dl = dseg * 128 + scol * 4;
                float4 v = make_float4(0.f, 0.f, 0.f, 0.f);
                if (u >= 0 && u < T_ && dl < 1000)
                    v = *reinterpret_cast<const float4*>(xb + (size_t)u * D_ + dbase + dl);
                *reinterpret_cast<float4*>(&xsl[rr][scol * 4]) = v;
            }
        }
    }
    for (int o = tid; o < 64 * K_; o += 256) {
        int tl = o / K_, k = o - tl * K_;
        wc[o] = coef[((size_t)nn * T_ + t0 + tl) * K_ + k];
    }
    __syncthreads();

    const int col = tid & 31;
    const int tsub = tid >> 5;
    const int tl0 = tsub * 8;
    float4 acc[8];
#pragma unroll
    for (int g = 0; g < 8; ++g) acc[g] = make_float4(0.f, 0.f, 0.f, 0.f);

#pragma unroll
    for (int ul = 0; ul < 28; ++ul) {                 // fully unrolled:
        const int rr = tl0 + ul;                      // k=ul-g is compile-time
        const float4 xf = *reinterpret_cast<const float4*>(&xsl[rr][col * 4]);
#pragma unroll
        for (int g = 0; g < 8; ++g) {
            const int k = ul - g;
            if (k >= 0 && k < K_) {
                const float c = wc[(tl0 + g) * K_ + k];
                acc[g].x = fmaf(c, xf.x, acc[g].x);
                acc[g].y = fmaf(c, xf.y, acc[g].y);
                acc[g].z = fmaf(c, xf.z, acc[g].z);
                acc[g].w = fmaf(c, xf.w, acc[g].w);
            }
        }
    }

    const int dl = dseg * 128 + col * 4;
    if (dl < 1000) {
#pragma unroll
        for (int g = 0; g < 8; ++g) {
            float* dst = out + ((size_t)nn * T_ + t0 + tl0 + g) * D_ + dbase + dl;
            *reinterpret_cast<float4*>(dst) = acc[g];
        }
    }
}

extern "C" void kernel_launch(void* const* d_in, const int* in_sizes, int n_in,
                              void* d_out, int out_size, void* d_ws, size_t ws_size,
                              hipStream_t stream) {
    const float* x  = (const float*)d_in[0];
    const float* W0 = (const float*)d_in[1];
    const float* W1 = (const float*)d_in[2];
    float* out = (float*)d_out;
    float* ws  = (float*)d_ws;

    const size_t CW = 344064;               // 16384*21
    float* W0p = ws;                        // 48000
    float* W1p = ws + 48000;                // 48000
    float* q0  = ws + 96000 + 0 * CW;
    float* q1  = ws + 96000 + 1 * CW;
    float* q2  = ws + 96000 + 2 * CW;
    float* q3  = ws + 96000 + 3 * CW;
    float* Ma  = ws + 96000 + 4 * CW;
    float* Mb  = ws + 96000 + 5 * CW;
    float* Pa  = ws + 96000 + 6 * CW;
    float* Pb  = ws + 96000 + 7 * CW;
    float* w0f = ws + 96000 + 8 * CW;
    float* w1f = ws + 96000 + 9 * CW;       // total ~14.2 MB

    hipLaunchKernelGGL(k_padW, dim3(188), dim3(256), 0, stream, W0, W1, W0p, W1p);
    hipLaunchKernelGGL(k_coef, dim3(1024), dim3(256), 0, stream,
                       x, W0p, W1p, q0, q1, q2, q3, Ma, Mb, Pa, Pb);
    hipLaunchKernelGGL(k_finish, dim3(1344), dim3(256), 0, stream,
                       q0, q1, q2, q3, Ma, Mb, Pa, Pb, w0f, w1f);
    hipLaunchKernelGGL(k_conv, dim3(4096), dim3(256), 0, stream, x, w0f, w1f, out);
}